// Round 3
// baseline (711.127 us; speedup 1.0000x reference)
//
#include <hip/hip_runtime.h>
#include <math.h>

#define TT 1024
#define JJ 64
#define HH 256
#define BB 2
#define H3 768

// ---- ws layout (floats) ----
#define OFF_Q        0u          // 2048*256 = 524288
#define OFF_K        524288u     // 128*256  = 32768
#define OFF_UVK      557056u     // 128*512  = 65536
#define OFF_SQ       622592u     // 2048
#define OFF_SQ2      624640u     // 2048
#define OFF_SK       626688u     // 128
#define OFF_SK2      626816u     // 128
#define OFF_WGU      626944u     // 256
#define OFF_WGV      627200u     // 256
#define OFF_CU       627456u     // 256
#define OFF_CV       627712u     // 256
#define OFF_WQB      627968u     // 512*256 = 131072
#define OFF_WKB      759040u     // 512*256 = 131072
#define OFF_BMAT     890112u     // 256*512 = 131072  (end 1021184 ~ 4.1MB)

// UVQ (2048*512 floats = 4MB) lives in d_out's bias region (8MB), consumed by
// main_fused before topk_bias overwrites it.

__device__ __forceinline__ float wave_reduce_add(float v) {
#pragma unroll
    for (int off = 32; off > 0; off >>= 1) v += __shfl_xor(v, off, 64);
    return v;
}

// ---- P1+P2 merged ----
__global__ __launch_bounds__(256) void prep_all(const float* __restrict__ Wu,
                                                const float* __restrict__ Wv,
                                                const float* __restrict__ g,
                                                const float* __restrict__ lb,
                                                const float* __restrict__ bu,
                                                const float* __restrict__ bv,
                                                float* __restrict__ ws) {
    int tid = threadIdx.x;
    if (blockIdx.x < 64) {
        int h = blockIdx.x * 4 + (tid >> 6);
        int lane = tid & 63;
        float su = 0.f, sv = 0.f, tu = 0.f, tv = 0.f;
#pragma unroll
        for (int i = 0; i < 12; i++) {
            int c = lane + 64 * i;
            float gg = g[c], bb = lb[c];
            float wu = Wu[h * H3 + c], wv = Wv[h * H3 + c];
            su += wu * gg; sv += wv * gg; tu += wu * bb; tv += wv * bb;
        }
        su = wave_reduce_add(su); sv = wave_reduce_add(sv);
        tu = wave_reduce_add(tu); tv = wave_reduce_add(tv);
        if (lane == 0) {
            ws[OFF_WGU + h] = su; ws[OFF_WGV + h] = sv;
            ws[OFF_CU + h] = tu + bu[h]; ws[OFF_CV + h] = tv + bv[h];
        }
    } else {
        int idx = (blockIdx.x - 64) * 256 + tid;  // = h*768 + c
        int h = idx / H3, c = idx % H3;
        float gg = g[c];
        float wu = Wu[idx] * gg, wv = Wv[idx] * gg;
        if (c < 256) {
            ws[OFF_WQB + h * 256 + c] = wu;
            ws[OFF_WQB + (256 + h) * 256 + c] = wv;
        } else if (c < 512) {
            int i = c - 256;
            ws[OFF_WKB + h * 256 + i] = wu;
            ws[OFF_WKB + (256 + h) * 256 + i] = wv;
        } else {
            int cc = c - 512;
            ws[OFF_BMAT + cc * 512 + 2 * h] = wu;
            ws[OFF_BMAT + cc * 512 + 2 * h + 1] = wv;
        }
    }
}

// ---- merged NT GEMM over two (A,B,C) triples: C = A * B^T ; 64x64 tile ----
__global__ __launch_bounds__(256) void gemm_nt2(const float* __restrict__ A1,
                                                const float* __restrict__ B1,
                                                float* __restrict__ C1, int nby1,
                                                const float* __restrict__ A2,
                                                const float* __restrict__ B2,
                                                float* __restrict__ C2,
                                                int N, int K) {
    __shared__ float As[16][68];
    __shared__ float Bs[16][68];
    int tid = threadIdx.x;
    int by = blockIdx.y;
    const float* A; const float* B; float* C; int m0;
    if (by < nby1) { A = A1; B = B1; C = C1; m0 = by * 64; }
    else           { A = A2; B = B2; C = C2; m0 = (by - nby1) * 64; }
    int n0 = blockIdx.x * 64;
    int tx = tid & 15, ty = tid >> 4;
    int sr = tid >> 2, sc = (tid & 3) * 4;
    float acc[4][4];
#pragma unroll
    for (int i = 0; i < 4; i++)
#pragma unroll
        for (int j = 0; j < 4; j++) acc[i][j] = 0.f;
    for (int k0 = 0; k0 < K; k0 += 16) {
        float4 av = *(const float4*)&A[(size_t)(m0 + sr) * K + k0 + sc];
        float4 bv = *(const float4*)&B[(size_t)(n0 + sr) * K + k0 + sc];
        As[sc + 0][sr] = av.x; As[sc + 1][sr] = av.y; As[sc + 2][sr] = av.z; As[sc + 3][sr] = av.w;
        Bs[sc + 0][sr] = bv.x; Bs[sc + 1][sr] = bv.y; Bs[sc + 2][sr] = bv.z; Bs[sc + 3][sr] = bv.w;
        __syncthreads();
#pragma unroll
        for (int kk = 0; kk < 16; kk++) {
            float a[4], b4[4];
            *(float4*)&a[0] = *(const float4*)&As[kk][4 * ty];
            *(float4*)&b4[0] = *(const float4*)&Bs[kk][4 * tx];
#pragma unroll
            for (int i = 0; i < 4; i++)
#pragma unroll
                for (int j = 0; j < 4; j++) acc[i][j] = fmaf(a[i], b4[j], acc[i][j]);
        }
        __syncthreads();
    }
#pragma unroll
    for (int i = 0; i < 4; i++)
#pragma unroll
        for (int j = 0; j < 4; j++)
            C[(size_t)(m0 + 4 * ty + i) * N + n0 + 4 * tx + j] = acc[i][j];
}

// ---- P3: per-row sums ----
__global__ void row_stats(float* __restrict__ ws) {
    int row = blockIdx.x, lane = threadIdx.x;
    const float* src = (row < 2048) ? (ws + OFF_Q + row * 256)
                                    : (ws + OFF_K + (row - 2048) * 256);
    float s = 0.f, s2 = 0.f;
#pragma unroll
    for (int i = 0; i < 4; i++) {
        float v = src[lane + 64 * i];
        s += v; s2 += v * v;
    }
    s = wave_reduce_add(s); s2 = wave_reduce_add(s2);
    if (lane == 0) {
        if (row < 2048) { ws[OFF_SQ + row] = s; ws[OFF_SQ2 + row] = s2; }
        else { ws[OFF_SK + row - 2048] = s; ws[OFF_SK2 + row - 2048] = s2; }
    }
}

// ---- main fused: 64-row tiles, 16x8 micro, LN-stats fused into staging ----
__global__ __launch_bounds__(256) void main_fused(const float* __restrict__ ws,
                                                  const float* __restrict__ UVQ,
                                                  const float* __restrict__ Wo,
                                                  const float* __restrict__ bo,
                                                  float* __restrict__ logits) {
    __shared__ float kk[256];
    __shared__ float As[16][68];   // [c][t]
    __shared__ float Bs[16 * 512];
    __shared__ float mu_s[64], inv_s[64];
    int tid = threadIdx.x;
    int t0 = blockIdx.x << 6;
    int j = blockIdx.y, b = blockIdx.z;
    int bj = (b << 6) | j;
    kk[tid] = ws[OFF_K + bj * 256 + tid];
    float acc[16][8];
#pragma unroll
    for (int m = 0; m < 16; m++)
#pragma unroll
        for (int i = 0; i < 8; i++) acc[m][i] = 0.f;
    int tc = tid & 63, tr = tid >> 6;
    int tl = tid >> 4, cl = tid & 15;
    const float* qbase = ws + OFF_Q + (size_t)((b << 10) + t0) * 256;
    const float4* BmatBase = (const float4*)(ws + OFF_BMAT);
    float4* Bs4 = (float4*)Bs;
    float s1[4] = {0.f, 0.f, 0.f, 0.f}, s2[4] = {0.f, 0.f, 0.f, 0.f};
    __syncthreads();  // kk ready
    for (int c0 = 0; c0 < 256; c0 += 16) {
        float kv = kk[c0 + cl];
        const float4* Bg = BmatBase + c0 * 128;
#pragma unroll
        for (int i = 0; i < 8; i++) Bs4[i * 256 + tid] = Bg[i * 256 + tid];
#pragma unroll
        for (int i = 0; i < 4; i++) {
            float v = qbase[(size_t)(tl + 16 * i) * 256 + c0 + cl];
            float av = v * kv;
            As[cl][tl + 16 * i] = av;
            s1[i] += av;
            s2[i] = fmaf(av, av, s2[i]);
        }
        __syncthreads();
#pragma unroll
        for (int kc = 0; kc < 16; kc++) {
            float a[16], bb[8];
            *(float4*)&a[0]  = *(const float4*)&As[kc][16 * tr];
            *(float4*)&a[4]  = *(const float4*)&As[kc][16 * tr + 4];
            *(float4*)&a[8]  = *(const float4*)&As[kc][16 * tr + 8];
            *(float4*)&a[12] = *(const float4*)&As[kc][16 * tr + 12];
            *(float4*)&bb[0] = *(const float4*)&Bs[kc * 512 + 4 * tc];
            *(float4*)&bb[4] = *(const float4*)&Bs[kc * 512 + 256 + 4 * tc];
#pragma unroll
            for (int m = 0; m < 16; m++)
#pragma unroll
                for (int i = 0; i < 8; i++) acc[m][i] = fmaf(a[m], bb[i], acc[m][i]);
        }
        __syncthreads();
    }
#pragma unroll
    for (int off = 1; off <= 8; off <<= 1) {
#pragma unroll
        for (int i = 0; i < 4; i++) {
            s1[i] += __shfl_xor(s1[i], off, 64);
            s2[i] += __shfl_xor(s2[i], off, 64);
        }
    }
    if (cl == 0) {
        float Sk = ws[OFF_SK + bj], Sk2 = ws[OFF_SK2 + bj];
#pragma unroll
        for (int i = 0; i < 4; i++) {
            int r = tl + 16 * i;
            int row = (b << 10) + t0 + r;
            float muv = (ws[OFF_SQ + row] + Sk + s1[i]) * (1.0f / 768.0f);
            float ex2 = (ws[OFF_SQ2 + row] + Sk2 + s2[i]) * (1.0f / 768.0f);
            mu_s[r] = muv;
            inv_s[r] = 1.0f / sqrtf(ex2 - muv * muv + 1e-5f);
        }
    }
    __syncthreads();
    int hs[4] = {2 * tc, 2 * tc + 1, 128 + 2 * tc, 129 + 2 * tc};
    float wgu_r[4], wgv_r[4], cu_r[4], cv_r[4], wo_r[4], uk_r[4], vk_r[4];
#pragma unroll
    for (int p = 0; p < 4; p++) {
        int h = hs[p];
        wgu_r[p] = ws[OFF_WGU + h]; wgv_r[p] = ws[OFF_WGV + h];
        cu_r[p] = ws[OFF_CU + h]; cv_r[p] = ws[OFF_CV + h];
        wo_r[p] = Wo[h];
        uk_r[p] = ws[OFF_UVK + bj * 512 + h];
        vk_r[p] = ws[OFF_UVK + bj * 512 + 256 + h];
    }
    float bo0 = bo[0];
#pragma unroll
    for (int m = 0; m < 16; m++) {
        int r = (tr << 4) + m;
        int row = (b << 10) + t0 + r;
        float muv = mu_s[r];
        float invv = inv_s[r];
        float part = 0.f;
#pragma unroll
        for (int p = 0; p < 4; p++) {
            float uq = UVQ[(size_t)row * 512 + hs[p]];
            float vq = UVQ[(size_t)row * 512 + 256 + hs[p]];
            float U = invv * (acc[m][2 * p] + uq + uk_r[p] - muv * wgu_r[p]) + cu_r[p];
            float V = invv * (acc[m][2 * p + 1] + vq + vk_r[p] - muv * wgv_r[p]) + cv_r[p];
            float ge = 0.5f * V * (1.0f + erff(V * 0.70710678118654752440f));
            part = fmaf(wo_r[p] * U, ge, part);
        }
        part = wave_reduce_add(part);
        if (tc == 0) logits[(size_t)row * 64 + j] = part + bo0;
    }
}

// ---- topk + softmax + bias expansion ----
__global__ void topk_bias(const float* __restrict__ logits, float* __restrict__ bias,
                          const int* __restrict__ p_cl, const int* __restrict__ p_L) {
    int row = blockIdx.x;
    int t = row & (TT - 1);
    int lane = threadIdx.x;
    __shared__ float pcb[64];
    float L = logits[(size_t)row * 64 + lane];
    float mx = L;
#pragma unroll
    for (int off = 32; off > 0; off >>= 1) mx = fmaxf(mx, __shfl_xor(mx, off, 64));
    float e = expf(L - mx);
    float s = wave_reduce_add(e);
    pcb[lane] = -8.0f * (1.0f - e / s);
    bool valid = (lane >= 5) && ((lane - 5) <= t);
    float val = (lane >= 5) ? (valid ? L : -INFINITY) : -INFINITY;
    int idv = (lane >= 5) ? lane : (1 << 28);
    unsigned long long selmask = 0x1Full;
    for (int it = 0; it < 11; it++) {
        float bv = val; int bi = idv;
#pragma unroll
        for (int off = 32; off > 0; off >>= 1) {
            float ov = __shfl_xor(bv, off, 64);
            int oi = __shfl_xor(bi, off, 64);
            if (ov > bv || (ov == bv && oi < bi)) { bv = ov; bi = oi; }
        }
        selmask |= 1ull << bi;
        if (lane == bi) { val = -INFINITY; idv = (1 << 27); }
    }
    __syncthreads();
    int clen = p_cl[0], Lctx = p_L[0];
    int nch1 = (Lctx + clen - 1) / clen - 1;
    float* brow = bias + (size_t)row * Lctx;
    for (int l = lane; l < Lctx; l += 64) {
        int c = l / clen;
        c = min(c, nch1); c = min(c, 63);
        float v;
        if (l > t) v = -1e30f;   // finite sentinel: ref has -inf, diff must not be nan
        else if ((selmask >> c) & 1ull) v = 0.0f;
        else v = pcb[c];
        brow[l] = v;
    }
}

extern "C" void kernel_launch(void* const* d_in, const int* in_sizes, int n_in,
                              void* d_out, int out_size, void* d_ws, size_t ws_size,
                              hipStream_t stream) {
    const float* Q   = (const float*)d_in[0];
    const float* Kin = (const float*)d_in[1];
    const float* Wq  = (const float*)d_in[2];
    const float* Wk  = (const float*)d_in[3];
    const float* g   = (const float*)d_in[4];
    const float* lb  = (const float*)d_in[5];
    const float* Wu  = (const float*)d_in[6];
    const float* bu  = (const float*)d_in[7];
    const float* Wv  = (const float*)d_in[8];
    const float* bv  = (const float*)d_in[9];
    const float* Wo  = (const float*)d_in[10];
    const float* bo  = (const float*)d_in[11];
    const int* p_cl  = (const int*)d_in[12];
    const int* p_L   = (const int*)d_in[13];
    float* ws = (float*)d_ws;
    float* logits = (float*)d_out;
    float* bias = (float*)d_out + (size_t)BB * TT * JJ;
    float* UVQ = bias;  // 4MB scratch inside bias region (consumed before topk_bias)

    prep_all<<<832, 256, 0, stream>>>(Wu, Wv, g, lb, bu, bv, ws);
    gemm_nt2<<<dim3(4, 34), 256, 0, stream>>>(Q, Wq, ws + OFF_Q, 32,
                                              Kin, Wk, ws + OFF_K, 256, 1024);
    row_stats<<<2176, 64, 0, stream>>>(ws);
    gemm_nt2<<<dim3(8, 34), 256, 0, stream>>>(ws + OFF_Q, ws + OFF_WQB, UVQ, 32,
                                              ws + OFF_K, ws + OFF_WKB, ws + OFF_UVK,
                                              512, 256);
    main_fused<<<dim3(16, 64, 2), 256, 0, stream>>>(ws, UVQ, Wo, bo, logits);
    topk_bias<<<2048, 64, 0, stream>>>(logits, bias, p_cl, p_L);
}

// Round 4
// 309.480 us; speedup vs baseline: 2.2978x; 2.2978x over previous
//
#include <hip/hip_runtime.h>
#include <math.h>

#define TT 1024
#define JJ 64
#define HH 256
#define BB 2
#define H3 768

// ---- ws layout (floats) ----
#define OFF_Q        0u          // 2048*256 = 524288
#define OFF_K        524288u     // 128*256  = 32768
#define OFF_UVK      557056u     // 128*512  = 65536
#define OFF_SQ       622592u     // 2048
#define OFF_SQ2      624640u     // 2048
#define OFF_SK       626688u     // 128
#define OFF_SK2      626816u     // 128
#define OFF_WGU      626944u     // 256
#define OFF_WGV      627200u     // 256
#define OFF_CU       627456u     // 256
#define OFF_CV       627712u     // 256
#define OFF_WQB      627968u     // 512*256 = 131072
#define OFF_WKB      759040u     // 512*256 = 131072
#define OFF_BPK      890112u     // 262144 bf16 (as 131072 floats): B frags, hi/lo split
// end 1021184 floats ~ 4.08 MB

// UVQ (2048*512 floats = 4MB) lives in d_out's bias region (consumed by
// main_mfma before topk_bias overwrites it).

typedef __attribute__((ext_vector_type(8))) short bf16x8;
typedef __attribute__((ext_vector_type(4))) float f32x4;

__device__ __forceinline__ short f2bf(float x) {
    unsigned u = __float_as_uint(x);
    unsigned r = (u + 0x7fffu + ((u >> 16) & 1u)) >> 16;   // RNE
    return (short)(r & 0xffffu);
}
__device__ __forceinline__ float bf2f(short s) {
    return __uint_as_float(((unsigned)(unsigned short)s) << 16);
}

__device__ __forceinline__ float wave_reduce_add(float v) {
#pragma unroll
    for (int off = 32; off > 0; off >>= 1) v += __shfl_xor(v, off, 64);
    return v;
}

// n-tile mapping: wave w owns global cols [w*128, w*128+128), nt local 0..7.
// h = w*64 + (nt>>1)*16 + (lane&15); nt even -> U, nt odd -> V.
// So for channel h, uv: ntg = (h>>6)*8 + ((h>>4)&3)*2 + uv, col-in-tile = h&15.

// ---- P1+P2: per-h scalars + WQB/WKB copies + BPK (split-bf16, frag-swizzled) ----
__global__ __launch_bounds__(256) void prep_all(const float* __restrict__ Wu,
                                                const float* __restrict__ Wv,
                                                const float* __restrict__ g,
                                                const float* __restrict__ lb,
                                                const float* __restrict__ bu,
                                                const float* __restrict__ bv,
                                                float* __restrict__ ws) {
    int tid = threadIdx.x;
    if (blockIdx.x < 64) {
        int h = blockIdx.x * 4 + (tid >> 6);
        int lane = tid & 63;
        float su = 0.f, sv = 0.f, tu = 0.f, tv = 0.f;
#pragma unroll
        for (int i = 0; i < 12; i++) {
            int c = lane + 64 * i;
            float gg = g[c], bb = lb[c];
            float wu = Wu[h * H3 + c], wv = Wv[h * H3 + c];
            su += wu * gg; sv += wv * gg; tu += wu * bb; tv += wv * bb;
        }
        su = wave_reduce_add(su); sv = wave_reduce_add(sv);
        tu = wave_reduce_add(tu); tv = wave_reduce_add(tv);
        if (lane == 0) {
            ws[OFF_WGU + h] = su; ws[OFF_WGV + h] = sv;
            ws[OFF_CU + h] = tu + bu[h]; ws[OFF_CV + h] = tv + bv[h];
        }
    } else {
        int idx = (blockIdx.x - 64) * 256 + tid;  // = h*768 + c
        int h = idx / H3, c = idx % H3;
        float gg = g[c];
        float wu = Wu[idx] * gg, wv = Wv[idx] * gg;
        if (c < 256) {
            ws[OFF_WQB + h * 256 + c] = wu;
            ws[OFF_WQB + (256 + h) * 256 + c] = wv;
        } else if (c < 512) {
            int i = c - 256;
            ws[OFF_WKB + h * 256 + i] = wu;
            ws[OFF_WKB + (256 + h) * 256 + i] = wv;
        } else {
            int cc = c - 512;                       // A-side channel 0..255
            short* bpk = (short*)(ws + OFF_BPK);
            int kc = cc >> 5, grp = (cc >> 3) & 3, j8 = cc & 7;
            int lane = grp * 16 + (h & 15);
#pragma unroll
            for (int uv = 0; uv < 2; uv++) {
                float val = uv ? wv : wu;
                int ntg = ((h >> 6) << 3) + (((h >> 4) & 3) << 1) + uv;
                size_t fb = (((size_t)(kc * 32 + ntg) * 2 + 0) * 64 + lane) * 8 + j8;
                short hi = f2bf(val);
                short lo = f2bf(val - bf2f(hi));
                bpk[fb] = hi;
                bpk[fb + 512] = lo;                 // p-stride = 64*8
            }
        }
    }
}

// ---- merged NT GEMM over two (A,B,C) triples: C = A * B^T ; 64x64 tile ----
__global__ __launch_bounds__(256) void gemm_nt2(const float* __restrict__ A1,
                                                const float* __restrict__ B1,
                                                float* __restrict__ C1, int nby1,
                                                const float* __restrict__ A2,
                                                const float* __restrict__ B2,
                                                float* __restrict__ C2,
                                                int N, int K) {
    __shared__ float As[16][68];
    __shared__ float Bs[16][68];
    int tid = threadIdx.x;
    int by = blockIdx.y;
    const float* A; const float* B; float* C; int m0;
    if (by < nby1) { A = A1; B = B1; C = C1; m0 = by * 64; }
    else           { A = A2; B = B2; C = C2; m0 = (by - nby1) * 64; }
    int n0 = blockIdx.x * 64;
    int tx = tid & 15, ty = tid >> 4;
    int sr = tid >> 2, sc = (tid & 3) * 4;
    float acc[4][4];
#pragma unroll
    for (int i = 0; i < 4; i++)
#pragma unroll
        for (int j = 0; j < 4; j++) acc[i][j] = 0.f;
    for (int k0 = 0; k0 < K; k0 += 16) {
        float4 av = *(const float4*)&A[(size_t)(m0 + sr) * K + k0 + sc];
        float4 bv = *(const float4*)&B[(size_t)(n0 + sr) * K + k0 + sc];
        As[sc + 0][sr] = av.x; As[sc + 1][sr] = av.y; As[sc + 2][sr] = av.z; As[sc + 3][sr] = av.w;
        Bs[sc + 0][sr] = bv.x; Bs[sc + 1][sr] = bv.y; Bs[sc + 2][sr] = bv.z; Bs[sc + 3][sr] = bv.w;
        __syncthreads();
#pragma unroll
        for (int kk = 0; kk < 16; kk++) {
            float a[4], b4[4];
            *(float4*)&a[0] = *(const float4*)&As[kk][4 * ty];
            *(float4*)&b4[0] = *(const float4*)&Bs[kk][4 * tx];
#pragma unroll
            for (int i = 0; i < 4; i++)
#pragma unroll
                for (int j = 0; j < 4; j++) acc[i][j] = fmaf(a[i], b4[j], acc[i][j]);
        }
        __syncthreads();
    }
#pragma unroll
    for (int i = 0; i < 4; i++)
#pragma unroll
        for (int j = 0; j < 4; j++)
            C[(size_t)(m0 + 4 * ty + i) * N + n0 + 4 * tx + j] = acc[i][j];
}

// ---- P3: per-row sums ----
__global__ void row_stats(float* __restrict__ ws) {
    int row = blockIdx.x, lane = threadIdx.x;
    const float* src = (row < 2048) ? (ws + OFF_Q + row * 256)
                                    : (ws + OFF_K + (row - 2048) * 256);
    float s = 0.f, s2 = 0.f;
#pragma unroll
    for (int i = 0; i < 4; i++) {
        float v = src[lane + 64 * i];
        s += v; s2 += v * v;
    }
    s = wave_reduce_add(s); s2 = wave_reduce_add(s2);
    if (lane == 0) {
        if (row < 2048) { ws[OFF_SQ + row] = s; ws[OFF_SQ2 + row] = s2; }
        else { ws[OFF_SK + row - 2048] = s; ws[OFF_SK2 + row - 2048] = s2; }
    }
}

// ---- main: split-bf16 MFMA GEMM (3-pass) + fused LN stats + epilogue ----
// Block: 256 thr = 4 waves. Tile M=64 (t-rows), N=512 (wave w: cols w*128..+128),
// K=256 in 8 chunks of 32. A (=q*k) staged fp32->hi/lo bf16 in dbuf LDS;
// B frags pre-swizzled in global (BPK), loaded coalesced to VGPRs (no LDS).
__global__ __launch_bounds__(256, 2) void main_mfma(const float* __restrict__ ws,
                                                    const float* __restrict__ UVQ,
                                                    const float* __restrict__ Wo,
                                                    const float* __restrict__ bo,
                                                    float* __restrict__ logits) {
    __shared__ float kk[256];
    __shared__ __align__(16) short Ah[2][64 * 32];
    __shared__ __align__(16) short Al[2][64 * 32];
    __shared__ float mu_s[64], inv_s[64];
    __shared__ float part_s[4][64];
    int tid = threadIdx.x;
    int t0 = blockIdx.x << 6;
    int j = blockIdx.y, b = blockIdx.z;
    int bj = (b << 6) | j;
    kk[tid] = ws[OFF_K + bj * 256 + tid];
    int w = tid >> 6, l = tid & 63;
    int c15 = l & 15, grp = l >> 4;
    int srow = tid >> 2, scol = (tid & 3) * 8;       // staging: row, col-offset
    const float* qrow = ws + OFF_Q + (size_t)((b << 10) + t0 + srow) * 256 + scol;
    const bf16x8* bpk = (const bf16x8*)(ws + OFF_BPK);
    f32x4 acc[4][8];
#pragma unroll
    for (int mt = 0; mt < 4; mt++)
#pragma unroll
        for (int nt = 0; nt < 8; nt++) acc[mt][nt] = (f32x4){0.f, 0.f, 0.f, 0.f};
    float s1 = 0.f, s2 = 0.f;
    __syncthreads();   // kk ready
    // stage chunk 0 into buf 0
    {
        float q8[8], kv[8];
        *(float4*)&q8[0] = *(const float4*)&qrow[0];
        *(float4*)&q8[4] = *(const float4*)&qrow[4];
        *(float4*)&kv[0] = *(const float4*)&kk[scol];
        *(float4*)&kv[4] = *(const float4*)&kk[scol + 4];
        bf16x8 vh, vl;
#pragma unroll
        for (int i = 0; i < 8; i++) {
            float av = q8[i] * kv[i];
            s1 += av; s2 = fmaf(av, av, s2);
            short hi = f2bf(av);
            vh[i] = hi;
            vl[i] = f2bf(av - bf2f(hi));
        }
        int ao = srow * 32 + scol;
        *(bf16x8*)&Ah[0][ao] = vh;
        *(bf16x8*)&Al[0][ao] = vl;
    }
    for (int kc = 0; kc < 8; kc++) {
        __syncthreads();   // buf[kc&1] ready
        int pb = kc & 1;
        // prefetch q for next chunk
        float q8[8];
        if (kc < 7) {
            *(float4*)&q8[0] = *(const float4*)&qrow[(kc + 1) * 32];
            *(float4*)&q8[4] = *(const float4*)&qrow[(kc + 1) * 32 + 4];
        }
        // A frags for this chunk (LDS -> regs, reused across 8 n-tiles)
        bf16x8 afh[4], afl[4];
#pragma unroll
        for (int mt = 0; mt < 4; mt++) {
            int ao = (mt * 16 + c15) * 32 + grp * 8;
            afh[mt] = *(const bf16x8*)&Ah[pb][ao];
            afl[mt] = *(const bf16x8*)&Al[pb][ao];
        }
#pragma unroll
        for (int nt = 0; nt < 8; nt++) {
            int ntg = w * 8 + nt;
            size_t fi = ((size_t)(kc * 32 + ntg) * 2) * 64 + l;
            bf16x8 bh = bpk[fi];
            bf16x8 bl = bpk[fi + 64];
#pragma unroll
            for (int mt = 0; mt < 4; mt++) {
                acc[mt][nt] = __builtin_amdgcn_mfma_f32_16x16x32_bf16(afl[mt], bh, acc[mt][nt], 0, 0, 0);
                acc[mt][nt] = __builtin_amdgcn_mfma_f32_16x16x32_bf16(afh[mt], bl, acc[mt][nt], 0, 0, 0);
                acc[mt][nt] = __builtin_amdgcn_mfma_f32_16x16x32_bf16(afh[mt], bh, acc[mt][nt], 0, 0, 0);
            }
        }
        if (kc < 7) {
            float kv[8];
            *(float4*)&kv[0] = *(const float4*)&kk[(kc + 1) * 32 + scol];
            *(float4*)&kv[4] = *(const float4*)&kk[(kc + 1) * 32 + scol + 4];
            bf16x8 vh, vl;
#pragma unroll
            for (int i = 0; i < 8; i++) {
                float av = q8[i] * kv[i];
                s1 += av; s2 = fmaf(av, av, s2);
                short hi = f2bf(av);
                vh[i] = hi;
                vl[i] = f2bf(av - bf2f(hi));
            }
            int ao = srow * 32 + scol;
            *(bf16x8*)&Ah[1 - pb][ao] = vh;
            *(bf16x8*)&Al[1 - pb][ao] = vl;
        }
    }
    // LN stats: reduce across the 4 staging threads of each row (adjacent lanes)
    s1 += __shfl_xor(s1, 1, 64); s1 += __shfl_xor(s1, 2, 64);
    s2 += __shfl_xor(s2, 1, 64); s2 += __shfl_xor(s2, 2, 64);
    if ((tid & 3) == 0) {
        int r = srow;
        int row = (b << 10) + t0 + r;
        float muv = (ws[OFF_SQ + row] + ws[OFF_SK + bj] + s1) * (1.0f / 768.0f);
        float ex2 = (ws[OFF_SQ2 + row] + ws[OFF_SK2 + bj] + s2) * (1.0f / 768.0f);
        mu_s[r] = muv;
        inv_s[r] = 1.0f / sqrtf(ex2 - muv * muv + 1e-5f);
    }
    __syncthreads();
    // epilogue: lane owns h = w*64 + a*16 + c15 (a=0..3); U at nt=2a, V at nt=2a+1
    float wgu_r[4], wgv_r[4], cu_r[4], cv_r[4], wo_r[4], uk_r[4], vk_r[4];
    int h4[4];
#pragma unroll
    for (int a = 0; a < 4; a++) {
        int h = (w << 6) + (a << 4) + c15;
        h4[a] = h;
        wgu_r[a] = ws[OFF_WGU + h]; wgv_r[a] = ws[OFF_WGV + h];
        cu_r[a] = ws[OFF_CU + h]; cv_r[a] = ws[OFF_CV + h];
        wo_r[a] = Wo[h];
        uk_r[a] = ws[OFF_UVK + bj * 512 + h];
        vk_r[a] = ws[OFF_UVK + bj * 512 + 256 + h];
    }
#pragma unroll
    for (int mt = 0; mt < 4; mt++) {
#pragma unroll
        for (int r4 = 0; r4 < 4; r4++) {
            int r = mt * 16 + grp * 4 + r4;
            int row = (b << 10) + t0 + r;
            float muv = mu_s[r], invv = inv_s[r];
            const float* uvq = UVQ + (size_t)row * 512;
            float part = 0.f;
#pragma unroll
            for (int a = 0; a < 4; a++) {
                float U = invv * (acc[mt][2 * a][r4] + uvq[h4[a]] + uk_r[a] - muv * wgu_r[a]) + cu_r[a];
                float V = invv * (acc[mt][2 * a + 1][r4] + uvq[256 + h4[a]] + vk_r[a] - muv * wgv_r[a]) + cv_r[a];
                float ge = 0.5f * V * (1.0f + erff(V * 0.70710678118654752440f));
                part = fmaf(wo_r[a] * U, ge, part);
            }
            part += __shfl_xor(part, 1, 64);
            part += __shfl_xor(part, 2, 64);
            part += __shfl_xor(part, 4, 64);
            part += __shfl_xor(part, 8, 64);
            if (c15 == 0) part_s[w][r] = part;
        }
    }
    __syncthreads();
    if (tid < 64) {
        float v = part_s[0][tid] + part_s[1][tid] + part_s[2][tid] + part_s[3][tid] + bo[0];
        logits[(size_t)((b << 10) + t0 + tid) * 64 + j] = v;
    }
}

// ---- topk + softmax + bias expansion ----
__global__ void topk_bias(const float* __restrict__ logits, float* __restrict__ bias,
                          const int* __restrict__ p_cl, const int* __restrict__ p_L) {
    int row = blockIdx.x;
    int t = row & (TT - 1);
    int lane = threadIdx.x;
    __shared__ float pcb[64];
    float L = logits[(size_t)row * 64 + lane];
    float mx = L;
#pragma unroll
    for (int off = 32; off > 0; off >>= 1) mx = fmaxf(mx, __shfl_xor(mx, off, 64));
    float e = expf(L - mx);
    float s = wave_reduce_add(e);
    pcb[lane] = -8.0f * (1.0f - e / s);
    bool valid = (lane >= 5) && ((lane - 5) <= t);
    float val = (lane >= 5) ? (valid ? L : -INFINITY) : -INFINITY;
    int idv = (lane >= 5) ? lane : (1 << 28);
    unsigned long long selmask = 0x1Full;
    for (int it = 0; it < 11; it++) {
        float bv = val; int bi = idv;
#pragma unroll
        for (int off = 32; off > 0; off >>= 1) {
            float ov = __shfl_xor(bv, off, 64);
            int oi = __shfl_xor(bi, off, 64);
            if (ov > bv || (ov == bv && oi < bi)) { bv = ov; bi = oi; }
        }
        selmask |= 1ull << bi;
        if (lane == bi) { val = -INFINITY; idv = (1 << 27); }
    }
    __syncthreads();
    int clen = p_cl[0], Lctx = p_L[0];
    int nch1 = (Lctx + clen - 1) / clen - 1;
    float* brow = bias + (size_t)row * Lctx;
    for (int ll = lane; ll < Lctx; ll += 64) {
        int c = ll / clen;
        c = min(c, nch1); c = min(c, 63);
        float v;
        if (ll > t) v = -1e30f;   // finite sentinel: ref has -inf, diff must not be nan
        else if ((selmask >> c) & 1ull) v = 0.0f;
        else v = pcb[c];
        brow[ll] = v;
    }
}

extern "C" void kernel_launch(void* const* d_in, const int* in_sizes, int n_in,
                              void* d_out, int out_size, void* d_ws, size_t ws_size,
                              hipStream_t stream) {
    const float* Q   = (const float*)d_in[0];
    const float* Kin = (const float*)d_in[1];
    const float* Wq  = (const float*)d_in[2];
    const float* Wk  = (const float*)d_in[3];
    const float* g   = (const float*)d_in[4];
    const float* lb  = (const float*)d_in[5];
    const float* Wu  = (const float*)d_in[6];
    const float* bu  = (const float*)d_in[7];
    const float* Wv  = (const float*)d_in[8];
    const float* bv  = (const float*)d_in[9];
    const float* Wo  = (const float*)d_in[10];
    const float* bo  = (const float*)d_in[11];
    const int* p_cl  = (const int*)d_in[12];
    const int* p_L   = (const int*)d_in[13];
    float* ws = (float*)d_ws;
    float* logits = (float*)d_out;
    float* bias = (float*)d_out + (size_t)BB * TT * JJ;
    float* UVQ = bias;  // 4MB scratch inside bias region (consumed before topk_bias)

    prep_all<<<832, 256, 0, stream>>>(Wu, Wv, g, lb, bu, bv, ws);
    gemm_nt2<<<dim3(4, 34), 256, 0, stream>>>(Q, Wq, ws + OFF_Q, 32,
                                              Kin, Wk, ws + OFF_K, 256, 1024);
    row_stats<<<2176, 64, 0, stream>>>(ws);
    gemm_nt2<<<dim3(8, 34), 256, 0, stream>>>(ws + OFF_Q, ws + OFF_WQB, UVQ, 32,
                                              ws + OFF_K, ws + OFF_WKB, ws + OFF_UVK,
                                              512, 256);
    main_mfma<<<dim3(16, 64, 2), 256, 0, stream>>>(ws, UVQ, Wo, bo, logits);
    topk_bias<<<2048, 64, 0, stream>>>(logits, bias, p_cl, p_L);
}

// Round 5
// 280.860 us; speedup vs baseline: 2.5320x; 1.1019x over previous
//
#include <hip/hip_runtime.h>
#include <hip/hip_bf16.h>
#include <math.h>

#define TT 1024
#define JJ 64
#define HH 256
#define BB 2
#define H3 768

// ---- ws layout (floats) ----
#define OFF_Q        0u          // 2048*256 = 524288
#define OFF_K        524288u     // 128*256  = 32768
#define OFF_UVK      557056u     // 128*512  = 65536
#define OFF_SQ       622592u     // 2048
#define OFF_SQ2      624640u     // 2048
#define OFF_SK       626688u     // 128
#define OFF_SK2      626816u     // 128  (SQ..SK2 contiguous 4352 floats, zeroed in prep)
#define OFF_WGU      626944u     // 256
#define OFF_WGV      627200u     // 256
#define OFF_CU       627456u     // 256
#define OFF_CV       627712u     // 256
#define OFF_WQB      627968u     // 512*256 = 131072
#define OFF_WKB      759040u     // 512*256 = 131072
#define OFF_BPK      890112u     // 262144 bf16 (as 131072 floats): B frags, hi/lo split
// end 1021184 floats ~ 4.08 MB

// UVQ (2048*512 floats = 4MB) lives in d_out's bias region (consumed by
// main_mfma before topk_bias overwrites it).

typedef __attribute__((ext_vector_type(8))) short bf16x8;
typedef __attribute__((ext_vector_type(4))) float f32x4;

__device__ __forceinline__ short f2bf(float x) {
    unsigned u = __float_as_uint(x);
    unsigned r = (u + 0x7fffu + ((u >> 16) & 1u)) >> 16;   // RNE
    return (short)(r & 0xffffu);
}
__device__ __forceinline__ float bf2f(short s) {
    return __uint_as_float(((unsigned)(unsigned short)s) << 16);
}

union bfu { __hip_bfloat162 h; short2 s; };

// split pair (a,b) into bf16 hi/lo via packed RNE converts
__device__ __forceinline__ void split2(float a, float b, short* hi2, short* lo2) {
    bfu h; h.h = __float22bfloat162_rn(float2{a, b});
    float fa = bf2f(h.s.x), fb = bf2f(h.s.y);
    bfu l; l.h = __float22bfloat162_rn(float2{a - fa, b - fb});
    hi2[0] = h.s.x; hi2[1] = h.s.y;
    lo2[0] = l.s.x; lo2[1] = l.s.y;
}

// branchless exact-gelu via Abramowitz-Stegun 7.1.26 erf (abs err ~1.5e-7)
__device__ __forceinline__ float gelu_fast(float v) {
    float ar = v * 0.70710678118654752440f;
    float a = fabsf(ar);
    float t = __builtin_amdgcn_rcpf(fmaf(0.3275911f, a, 1.0f));
    float p = fmaf(fmaf(fmaf(fmaf(1.061405429f, t, -1.453152027f), t,
                             1.421413741f), t, -0.284496736f), t, 0.254829592f) * t;
    float e = __expf(-ar * ar);
    float er = fmaf(-p, e, 1.0f);
    er = copysignf(er, ar);
    return 0.5f * v * (1.0f + er);
}

__device__ __forceinline__ float wave_reduce_add(float v) {
#pragma unroll
    for (int off = 32; off > 0; off >>= 1) v += __shfl_xor(v, off, 64);
    return v;
}

// ---- P1+P2+zero: per-h scalars + WQB/WKB copies + BPK frags + stats zeroing ----
__global__ __launch_bounds__(256) void prep_all(const float* __restrict__ Wu,
                                                const float* __restrict__ Wv,
                                                const float* __restrict__ g,
                                                const float* __restrict__ lb,
                                                const float* __restrict__ bu,
                                                const float* __restrict__ bv,
                                                float* __restrict__ ws) {
    int tid = threadIdx.x;
    if (blockIdx.x >= 832) {
        int idx = (blockIdx.x - 832) * 256 + tid;   // 0..4351
        ws[OFF_SQ + idx] = 0.0f;
        return;
    }
    if (blockIdx.x < 64) {
        int h = blockIdx.x * 4 + (tid >> 6);
        int lane = tid & 63;
        float su = 0.f, sv = 0.f, tu = 0.f, tv = 0.f;
#pragma unroll
        for (int i = 0; i < 12; i++) {
            int c = lane + 64 * i;
            float gg = g[c], bb = lb[c];
            float wu = Wu[h * H3 + c], wv = Wv[h * H3 + c];
            su += wu * gg; sv += wv * gg; tu += wu * bb; tv += wv * bb;
        }
        su = wave_reduce_add(su); sv = wave_reduce_add(sv);
        tu = wave_reduce_add(tu); tv = wave_reduce_add(tv);
        if (lane == 0) {
            ws[OFF_WGU + h] = su; ws[OFF_WGV + h] = sv;
            ws[OFF_CU + h] = tu + bu[h]; ws[OFF_CV + h] = tv + bv[h];
        }
    } else {
        int idx = (blockIdx.x - 64) * 256 + tid;  // = h*768 + c
        int h = idx / H3, c = idx % H3;
        float gg = g[c];
        float wu = Wu[idx] * gg, wv = Wv[idx] * gg;
        if (c < 256) {
            ws[OFF_WQB + h * 256 + c] = wu;
            ws[OFF_WQB + (256 + h) * 256 + c] = wv;
        } else if (c < 512) {
            int i = c - 256;
            ws[OFF_WKB + h * 256 + i] = wu;
            ws[OFF_WKB + (256 + h) * 256 + i] = wv;
        } else {
            int cc = c - 512;                       // A-side channel 0..255
            short* bpk = (short*)(ws + OFF_BPK);
            int kc = cc >> 5, grp = (cc >> 3) & 3, j8 = cc & 7;
            int lane = grp * 16 + (h & 15);
#pragma unroll
            for (int uv = 0; uv < 2; uv++) {
                float val = uv ? wv : wu;
                int ntg = ((h >> 6) << 3) + (((h >> 4) & 3) << 1) + uv;
                size_t fb = (((size_t)(kc * 32 + ntg) * 2 + 0) * 64 + lane) * 8 + j8;
                short hi = f2bf(val);
                short lo = f2bf(val - bf2f(hi));
                bpk[fb] = hi;
                bpk[fb + 512] = lo;                 // p-stride = 64*8
            }
        }
    }
}

// ---- merged NT GEMM over two (A,B,C) triples; optional fused row sum/sumsq ----
__global__ __launch_bounds__(256) void gemm_nt2(const float* __restrict__ A1,
                                                const float* __restrict__ B1,
                                                float* __restrict__ C1, int nby1,
                                                const float* __restrict__ A2,
                                                const float* __restrict__ B2,
                                                float* __restrict__ C2,
                                                int N, int K,
                                                float* __restrict__ S1a,
                                                float* __restrict__ S2a,
                                                float* __restrict__ S1b,
                                                float* __restrict__ S2b) {
    __shared__ float As[16][68];
    __shared__ float Bs[16][68];
    int tid = threadIdx.x;
    int by = blockIdx.y;
    const float* A; const float* B; float* C; int m0; float* St1; float* St2;
    if (by < nby1) { A = A1; B = B1; C = C1; m0 = by * 64; St1 = S1a; St2 = S2a; }
    else { A = A2; B = B2; C = C2; m0 = (by - nby1) * 64; St1 = S1b; St2 = S2b; }
    int n0 = blockIdx.x * 64;
    int tx = tid & 15, ty = tid >> 4;
    int sr = tid >> 2, sc = (tid & 3) * 4;
    float acc[4][4];
#pragma unroll
    for (int i = 0; i < 4; i++)
#pragma unroll
        for (int j = 0; j < 4; j++) acc[i][j] = 0.f;
    for (int k0 = 0; k0 < K; k0 += 16) {
        float4 av = *(const float4*)&A[(size_t)(m0 + sr) * K + k0 + sc];
        float4 bv = *(const float4*)&B[(size_t)(n0 + sr) * K + k0 + sc];
        As[sc + 0][sr] = av.x; As[sc + 1][sr] = av.y; As[sc + 2][sr] = av.z; As[sc + 3][sr] = av.w;
        Bs[sc + 0][sr] = bv.x; Bs[sc + 1][sr] = bv.y; Bs[sc + 2][sr] = bv.z; Bs[sc + 3][sr] = bv.w;
        __syncthreads();
#pragma unroll
        for (int kk = 0; kk < 16; kk++) {
            float a[4], b4[4];
            *(float4*)&a[0] = *(const float4*)&As[kk][4 * ty];
            *(float4*)&b4[0] = *(const float4*)&Bs[kk][4 * tx];
#pragma unroll
            for (int i = 0; i < 4; i++)
#pragma unroll
                for (int j = 0; j < 4; j++) acc[i][j] = fmaf(a[i], b4[j], acc[i][j]);
        }
        __syncthreads();
    }
#pragma unroll
    for (int i = 0; i < 4; i++)
#pragma unroll
        for (int j = 0; j < 4; j++)
            C[(size_t)(m0 + 4 * ty + i) * N + n0 + 4 * tx + j] = acc[i][j];
    if (St1) {
        // fused row stats: per row partial sum/sumsq over this block's 64 cols
#pragma unroll
        for (int i = 0; i < 4; i++) {
            float s = 0.f, s2 = 0.f;
#pragma unroll
            for (int j = 0; j < 4; j++) {
                float v = acc[i][j];
                s += v; s2 = fmaf(v, v, s2);
            }
#pragma unroll
            for (int off = 1; off <= 8; off <<= 1) {
                s += __shfl_xor(s, off, 64);
                s2 += __shfl_xor(s2, off, 64);
            }
            if (tx == 0) {
                atomicAdd(&St1[m0 + 4 * ty + i], s);
                atomicAdd(&St2[m0 + 4 * ty + i], s2);
            }
        }
    }
}

// ---- main: split-bf16 MFMA (3-pass), A staged once, 1 barrier K-phase ----
// Block: 4 waves. Tile M=64, N=512 (wave w: cols w*128..+128), K=256.
__global__ __launch_bounds__(256, 2) void main_mfma(const float* __restrict__ ws,
                                                    const float* __restrict__ UVQ,
                                                    const float* __restrict__ Wo,
                                                    const float* __restrict__ bo,
                                                    float* __restrict__ logits) {
    __shared__ __align__(16) short Ah[8][64 * 32];   // 32 KB
    __shared__ __align__(16) short Al[8][64 * 32];   // 32 KB
    __shared__ float mu_s[64], inv_s[64];
    __shared__ float part_s[4][64];
    int tid = threadIdx.x;
    int t0 = blockIdx.x << 6;
    int j = blockIdx.y, b = blockIdx.z;
    int bj = (b << 6) | j;
    int w = tid >> 6, l = tid & 63;
    int c15 = l & 15, grp = l >> 4;
    int srow = tid >> 2, scol = (tid & 3) * 8;
    const float* qrow = ws + OFF_Q + (size_t)((b << 10) + t0 + srow) * 256 + scol;
    const float* krow = ws + OFF_K + (size_t)bj * 256 + scol;
    const bf16x8* bpk = (const bf16x8*)(ws + OFF_BPK);
    f32x4 acc[4][8];
#pragma unroll
    for (int mt = 0; mt < 4; mt++)
#pragma unroll
        for (int nt = 0; nt < 8; nt++) acc[mt][nt] = (f32x4){0.f, 0.f, 0.f, 0.f};
    // ---- stage all of A (=q*k split hi/lo) once; LN stats on the fly ----
    float s1 = 0.f, s2 = 0.f;
#pragma unroll
    for (int kc = 0; kc < 8; kc++) {
        float q8[8], kv[8];
        *(float4*)&q8[0] = *(const float4*)&qrow[kc * 32];
        *(float4*)&q8[4] = *(const float4*)&qrow[kc * 32 + 4];
        *(float4*)&kv[0] = *(const float4*)&krow[kc * 32];
        *(float4*)&kv[4] = *(const float4*)&krow[kc * 32 + 4];
        bf16x8 vh, vl;
        short htmp[2], ltmp[2];
#pragma unroll
        for (int i = 0; i < 4; i++) {
            float a = q8[2 * i] * kv[2 * i];
            float c = q8[2 * i + 1] * kv[2 * i + 1];
            s1 += a + c;
            s2 = fmaf(a, a, s2); s2 = fmaf(c, c, s2);
            split2(a, c, htmp, ltmp);
            vh[2 * i] = htmp[0]; vh[2 * i + 1] = htmp[1];
            vl[2 * i] = ltmp[0]; vl[2 * i + 1] = ltmp[1];
        }
        int ao = srow * 32 + scol;
        *(bf16x8*)&Ah[kc][ao] = vh;
        *(bf16x8*)&Al[kc][ao] = vl;
    }
    s1 += __shfl_xor(s1, 1, 64); s1 += __shfl_xor(s1, 2, 64);
    s2 += __shfl_xor(s2, 1, 64); s2 += __shfl_xor(s2, 2, 64);
    if ((tid & 3) == 0) {
        int row = (b << 10) + t0 + srow;
        float muv = (ws[OFF_SQ + row] + ws[OFF_SK + bj] + s1) * (1.0f / 768.0f);
        float ex2 = (ws[OFF_SQ2 + row] + ws[OFF_SK2 + bj] + s2) * (1.0f / 768.0f);
        mu_s[srow] = muv;
        inv_s[srow] = 1.0f / sqrtf(ex2 - muv * muv + 1e-5f);
    }
    __syncthreads();
    // ---- K-loop: pure global B-frag loads + MFMA (no barriers) ----
    const bf16x8* bpw = bpk + (size_t)(w * 8) * 128 + l;
#pragma unroll
    for (int kc = 0; kc < 8; kc++) {
        bf16x8 afh[4], afl[4];
#pragma unroll
        for (int mt = 0; mt < 4; mt++) {
            int ao = (mt * 16 + c15) * 32 + grp * 8;
            afh[mt] = *(const bf16x8*)&Ah[kc][ao];
            afl[mt] = *(const bf16x8*)&Al[kc][ao];
        }
        const bf16x8* bpc = bpw + (size_t)kc * 4096;
#pragma unroll
        for (int nt = 0; nt < 8; nt++) {
            bf16x8 bh = bpc[nt * 128];
            bf16x8 bl = bpc[nt * 128 + 64];
            // same-acc MFMAs spaced 4 apart (independent across mt)
#pragma unroll
            for (int mt = 0; mt < 4; mt++)
                acc[mt][nt] = __builtin_amdgcn_mfma_f32_16x16x32_bf16(afl[mt], bh, acc[mt][nt], 0, 0, 0);
#pragma unroll
            for (int mt = 0; mt < 4; mt++)
                acc[mt][nt] = __builtin_amdgcn_mfma_f32_16x16x32_bf16(afh[mt], bl, acc[mt][nt], 0, 0, 0);
#pragma unroll
            for (int mt = 0; mt < 4; mt++)
                acc[mt][nt] = __builtin_amdgcn_mfma_f32_16x16x32_bf16(afh[mt], bh, acc[mt][nt], 0, 0, 0);
        }
    }
    // ---- epilogue: lane owns h = w*64 + a*16 + c15; U at nt=2a, V at nt=2a+1 ----
    float wgu_r[4], wgv_r[4], cu_r[4], cv_r[4], wo_r[4], uk_r[4], vk_r[4];
    int h4[4];
#pragma unroll
    for (int a = 0; a < 4; a++) {
        int h = (w << 6) + (a << 4) + c15;
        h4[a] = h;
        wgu_r[a] = ws[OFF_WGU + h]; wgv_r[a] = ws[OFF_WGV + h];
        cu_r[a] = ws[OFF_CU + h]; cv_r[a] = ws[OFF_CV + h];
        wo_r[a] = Wo[h];
        uk_r[a] = ws[OFF_UVK + bj * 512 + h];
        vk_r[a] = ws[OFF_UVK + bj * 512 + 256 + h];
    }
#pragma unroll
    for (int mt = 0; mt < 4; mt++) {
#pragma unroll
        for (int r4 = 0; r4 < 4; r4++) {
            int r = mt * 16 + grp * 4 + r4;
            int row = (b << 10) + t0 + r;
            float muv = mu_s[r], invv = inv_s[r];
            const float* uvq = UVQ + (size_t)row * 512;
            float part = 0.f;
#pragma unroll
            for (int a = 0; a < 4; a++) {
                float U = invv * (acc[mt][2 * a][r4] + uvq[h4[a]] + uk_r[a] - muv * wgu_r[a]) + cu_r[a];
                float V = invv * (acc[mt][2 * a + 1][r4] + uvq[256 + h4[a]] + vk_r[a] - muv * wgv_r[a]) + cv_r[a];
                part = fmaf(wo_r[a] * U, gelu_fast(V), part);
            }
            part += __shfl_xor(part, 1, 64);
            part += __shfl_xor(part, 2, 64);
            part += __shfl_xor(part, 4, 64);
            part += __shfl_xor(part, 8, 64);
            if (c15 == 0) part_s[w][r] = part;
        }
    }
    __syncthreads();
    if (tid < 64) {
        float v = part_s[0][tid] + part_s[1][tid] + part_s[2][tid] + part_s[3][tid] + bo[0];
        logits[(size_t)((b << 10) + t0 + tid) * 64 + j] = v;
    }
}

// ---- topk + softmax + bias expansion ----
__global__ void topk_bias(const float* __restrict__ logits, float* __restrict__ bias,
                          const int* __restrict__ p_cl, const int* __restrict__ p_L) {
    int row = blockIdx.x;
    int t = row & (TT - 1);
    int lane = threadIdx.x;
    __shared__ float pcb[64];
    float L = logits[(size_t)row * 64 + lane];
    float mx = L;
#pragma unroll
    for (int off = 32; off > 0; off >>= 1) mx = fmaxf(mx, __shfl_xor(mx, off, 64));
    float e = expf(L - mx);
    float s = wave_reduce_add(e);
    pcb[lane] = -8.0f * (1.0f - e / s);
    bool valid = (lane >= 5) && ((lane - 5) <= t);
    float val = (lane >= 5) ? (valid ? L : -INFINITY) : -INFINITY;
    int idv = (lane >= 5) ? lane : (1 << 28);
    unsigned long long selmask = 0x1Full;
    for (int it = 0; it < 11; it++) {
        float bv = val; int bi = idv;
#pragma unroll
        for (int off = 32; off > 0; off >>= 1) {
            float ov = __shfl_xor(bv, off, 64);
            int oi = __shfl_xor(bi, off, 64);
            if (ov > bv || (ov == bv && oi < bi)) { bv = ov; bi = oi; }
        }
        selmask |= 1ull << bi;
        if (lane == bi) { val = -INFINITY; idv = (1 << 27); }
    }
    __syncthreads();
    int clen = p_cl[0], Lctx = p_L[0];
    int nch1 = (Lctx + clen - 1) / clen - 1;
    float* brow = bias + (size_t)row * Lctx;
    for (int ll = lane; ll < Lctx; ll += 64) {
        int c = ll / clen;
        c = min(c, nch1); c = min(c, 63);
        float v;
        if (ll > t) v = -1e30f;   // finite sentinel: ref has -inf, diff must not be nan
        else if ((selmask >> c) & 1ull) v = 0.0f;
        else v = pcb[c];
        brow[ll] = v;
    }
}

extern "C" void kernel_launch(void* const* d_in, const int* in_sizes, int n_in,
                              void* d_out, int out_size, void* d_ws, size_t ws_size,
                              hipStream_t stream) {
    const float* Q   = (const float*)d_in[0];
    const float* Kin = (const float*)d_in[1];
    const float* Wq  = (const float*)d_in[2];
    const float* Wk  = (const float*)d_in[3];
    const float* g   = (const float*)d_in[4];
    const float* lb  = (const float*)d_in[5];
    const float* Wu  = (const float*)d_in[6];
    const float* bu  = (const float*)d_in[7];
    const float* Wv  = (const float*)d_in[8];
    const float* bv  = (const float*)d_in[9];
    const float* Wo  = (const float*)d_in[10];
    const float* bo  = (const float*)d_in[11];
    const int* p_cl  = (const int*)d_in[12];
    const int* p_L   = (const int*)d_in[13];
    float* ws = (float*)d_ws;
    float* logits = (float*)d_out;
    float* bias = (float*)d_out + (size_t)BB * TT * JJ;
    float* UVQ = bias;  // 4MB scratch inside bias region (consumed before topk_bias)

    prep_all<<<849, 256, 0, stream>>>(Wu, Wv, g, lb, bu, bv, ws);
    gemm_nt2<<<dim3(4, 34), 256, 0, stream>>>(Q, Wq, ws + OFF_Q, 32,
                                              Kin, Wk, ws + OFF_K, 256, 1024,
                                              ws + OFF_SQ, ws + OFF_SQ2,
                                              ws + OFF_SK, ws + OFF_SK2);
    gemm_nt2<<<dim3(8, 34), 256, 0, stream>>>(ws + OFF_Q, ws + OFF_WQB, UVQ, 32,
                                              ws + OFF_K, ws + OFF_WKB, ws + OFF_UVK,
                                              512, 256,
                                              nullptr, nullptr, nullptr, nullptr);
    main_mfma<<<dim3(16, 64, 2), 256, 0, stream>>>(ws, UVQ, Wo, bo, logits);
    topk_bias<<<2048, 64, 0, stream>>>(logits, bias, p_cl, p_L);
}